// Round 1
// baseline (803.158 us; speedup 1.0000x reference)
//
#include <hip/hip_runtime.h>
#include <math.h>

#define BATCH 32
#define NN 1024
#define MM 1024
#define RR 4                    // rows per lane
#define CC 4                    // cols per superstep
#define LANES 64
#define NWAVE 4                 // pipeline ROLES (folded onto 2 hardware waves)
#define TPB (MM / 4)            // tile-columns = lane-local supersteps (256)
#define NSUP (TPB + LANES - 1)  // 319 supersteps per role
#define LAG 72                  // role-to-role lag (63 lane skew + 8 barrier margin + 1)
#define TOT (NSUP + (NWAVE - 1) * LAG)   // 535 iterations
#define DEPTH 32                // LDS boundary ring depth (float4 entries)
#define DEC_WORDS_PER_BATCH ((NN / 4) * (MM / 4))     // 65536
#define DEC_BYTES ((size_t)BATCH * DEC_WORDS_PER_BATCH * 4)   // 8 MB
#define REQ_WS DEC_BYTES
#define LPATH (NN + MM - 1)     // 2047

__global__ void init_kernel(float* out) { out[0] = 0.0f; }

// ---- Backtrack word-walk (4x4 tile words, 3-candidate prefetch) -------------
__device__ inline void bt_walk4(const unsigned* __restrict__ sdec, int roff,
                                int iLow, int& i, int& j, int& n,
                                unsigned* __restrict__ path)
{
    int ri = i >> 2, jc = j >> 2;
    unsigned w = sdec[(ri - roff) * 256 + jc];
    while (true) {
        const int base = (ri - roff) * 256 + jc;
        const unsigned wl = sdec[(jc > 0)    ? base - 1   : base];
        const unsigned wu = sdec[(ri > roff) ? base - 256 : base];
        const unsigned wd = sdec[(ri > roff && jc > 0) ? base - 257 : base];
        bool done = false, susp = false;
        while (true) {
            path[n++] = ((unsigned)i << 16) | (unsigned)j;
            if ((i | j) == 0) { done = true; break; }
            const unsigned m = (w >> (((i & 3) * 4 + (j & 3)) * 2)) & 3u;
            i -= (m != 2u); j -= (m != 1u);
            if (i < iLow) { susp = true; break; }
            if ((i >> 2) != ri || (j >> 2) != jc) break;
        }
        if (done || susp) break;
        const int nri = i >> 2, njc = j >> 2;
        w = (nri == ri) ? wl : ((njc == jc) ? wu : wd);
        ri = nri; jc = njc;
    }
}

// ---- Per-stream DP state ----------------------------------------------------
// Two independent pipeline streams live in each wave; dp_step is a verbatim
// copy of the proven 4-wave superstep body, parameterized by role. FP op order
// per role is identical to the 4-wave version => bit-identical decisions/loss.
struct SS {
    float Dp[RR], Dbot[CC], bv[CC], bndRet;
    float px[RR], py[RR];
    float4 tx4, ty4, gcur;
    unsigned* decT;
};

__device__ __forceinline__ void dp_step(SS& S, const int u, const int role,
                                        const int l, const int bpa,
                                        const float* __restrict__ txA,
                                        const float* __restrict__ tyA,
                                        float4* __restrict__ ringW,
                                        const float4* __restrict__ ringR)
{
    const float INF = __builtin_inff();
    const int ul = u - LAG * role;       // this stream's local superstep
    if (l == 0) {                        // boundary row from previous band
        const bool gb = (role > 0) && (ul >= 0) && (ul < TPB);
        S.bv[0] = gb ? S.gcur.x : INF; S.bv[1] = gb ? S.gcur.y : INF;
        S.bv[2] = gb ? S.gcur.z : INF; S.bv[3] = gb ? S.gcur.w : INF;
    }
    const bool act = (ul >= l) && (ul < l + TPB);
    if (act) {
        const int j0 = CC * (ul - l);
        const float cx[CC] = {S.tx4.x, S.tx4.y, S.tx4.z, S.tx4.w};
        const float cy[CC] = {S.ty4.x, S.ty4.y, S.ty4.z, S.ty4.w};
        float cost[RR][CC];
        #pragma unroll
        for (int c = 0; c < CC; ++c)
            #pragma unroll
            for (int r = 0; r < RR; ++r) {
                const float dx = S.px[r] - cx[c], dy = S.py[r] - cy[c];
                cost[r][c] = __builtin_amdgcn_sqrtf(dx * dx + dy * dy);
            }
        unsigned word = 0;
        #pragma unroll
        for (int c = 0; c < CC; ++c) {
            float up = S.bv[c];                     // D[i0-1][j0+c]
            float dg = (c == 0) ? S.bndRet : S.bv[c - 1];
            #pragma unroll
            for (int r = 0; r < RR; ++r) {
                const float lf = S.Dp[r];           // D[i0+r][j0+c-1]
                // JAX argmin over [dg, up, lf], first-minimum tie order.
                const unsigned m = (dg <= up && dg <= lf) ? 0u
                                 : ((up <= lf) ? 1u : 2u);
                const float D = cost[r][c] + fminf(dg, fminf(up, lf));
                word |= m << ((r * 4 + c) * 2);
                dg = lf; up = D; S.Dp[r] = D;
            }
            S.Dbot[c] = up;
        }
        S.decT[j0 >> 2] = word;
        if (l == LANES - 1 && role < NWAVE - 1)     // publish bottom row
            ringW[ul & (DEPTH - 1)] =
                make_float4(S.Dbot[0], S.Dbot[1], S.Dbot[2], S.Dbot[3]);
    }
    // Uniform epilogue: retain dg, exchange boundary, prefetch next.
    S.bndRet = S.bv[CC - 1];
    // Raw ds_bpermute (pull from lane l-1). Lane 0 pulls garbage (lane 63),
    // but lane 0's bv[] is fully overwritten by the l==0 block at the top of
    // the next step before any use, and bndRet is read above (pre-shuffle).
    #pragma unroll
    for (int c = 0; c < CC; ++c)
        S.bv[c] = __int_as_float(
            __builtin_amdgcn_ds_bpermute(bpa, __float_as_int(S.Dbot[c])));
    const int un = ul + 1;
    if (un >= l && un < l + TPB) {
        const int jn = CC * (un - l);
        S.tx4 = ((const float4*)txA)[jn >> 2];
        S.ty4 = ((const float4*)tyA)[jn >> 2];
    }
    if (l == 0 && role > 0 && un >= 0 && un < TPB)
        S.gcur = ringR[(un + 63) & (DEPTH - 1)];
}

// ---- Fused DP + backtrack: 32 blocks (one per batch) x 128 threads ----------
// The former 4-wave pipeline (roles 0..3, LAG=72) is folded onto 2 hardware
// waves, each carrying TWO register streams: wave w runs role w and role w+2
// back-to-back every iteration. Schedule, ring discipline (write at iter X,
// read at X+8, >=1 barrier between via the u&7 cadence) and numerics are
// identical to the 4-wave version; the second stream exists purely to fill
// each wave's dependency/LDS-latency stalls with independent work (1 wave/SIMD
// => no TLP; per-SIMD VALU issue was ~23%).
__global__ __launch_bounds__(128, 1) void dtw_fused(
    const float* __restrict__ preds, const float* __restrict__ targs,
    const float* __restrict__ subcoef, unsigned* __restrict__ dec,
    float* __restrict__ out)
{
    const int b = blockIdx.x, t = threadIdx.x;
    const int l = t & 63, w = t >> 6;          // w in {0,1}
    const float INF = __builtin_inff();

    __shared__ float pxA[NN], pyA[NN], txA[MM], tyA[MM];   // 16 KB
    __shared__ float4 ring[NWAVE - 1][DEPTH];              // 1.5 KB
    __shared__ unsigned sdec[128 * 256];                   // 128 KB
    __shared__ unsigned path[LPATH + 1];                   // 8 KB
    __shared__ int sI, sJ, sN;
    __shared__ float wsum[NWAVE];

    for (int it = 0; it < NN / 128; ++it) {
        const int idx = it * 128 + t;
        const float4 p4 = ((const float4*)preds)[(size_t)b * NN + idx];
        pxA[idx] = p4.x; pyA[idx] = p4.y;
        const float4 t4 = ((const float4*)targs)[(size_t)b * MM + idx];
        txA[idx] = t4.x; tyA[idx] = t4.y;
    }
    __syncthreads();

    // ---------------- DP ----------------
    const int bpa = (l - 1) << 2;              // ds_bpermute byte index
    const int roleA = w, roleB = w + 2;
    SS A, B;
    {
        const int i0a = (roleA << 8) + (l << 2);
        const int i0b = (roleB << 8) + (l << 2);
        const float4 pxa = ((const float4*)pxA)[i0a >> 2];
        const float4 pya = ((const float4*)pyA)[i0a >> 2];
        const float4 pxb = ((const float4*)pxA)[i0b >> 2];
        const float4 pyb = ((const float4*)pyA)[i0b >> 2];
        A.px[0] = pxa.x; A.px[1] = pxa.y; A.px[2] = pxa.z; A.px[3] = pxa.w;
        A.py[0] = pya.x; A.py[1] = pya.y; A.py[2] = pya.z; A.py[3] = pya.w;
        B.px[0] = pxb.x; B.px[1] = pxb.y; B.px[2] = pxb.z; B.px[3] = pxb.w;
        B.py[0] = pyb.x; B.py[1] = pyb.y; B.py[2] = pyb.z; B.py[3] = pyb.w;
        A.decT = dec + (size_t)b * DEC_WORDS_PER_BATCH + (size_t)(i0a >> 2) * TPB;
        B.decT = dec + (size_t)b * DEC_WORDS_PER_BATCH + (size_t)(i0b >> 2) * TPB;
    }
    #pragma unroll
    for (int r = 0; r < RR; ++r) { A.Dp[r] = INF; B.Dp[r] = INF; }
    #pragma unroll
    for (int c = 0; c < CC; ++c) {
        A.Dbot[c] = INF; A.bv[c] = INF;
        B.Dbot[c] = INF; B.bv[c] = INF;
    }
    // dg seed: only global (0,0) gets the inf->0 substitution (role 0, lane 0).
    A.bndRet = (roleA == 0 && l == 0) ? 0.0f : INF;
    B.bndRet = INF;
    A.gcur = make_float4(INF, INF, INF, INF);
    B.gcur = make_float4(INF, INF, INF, INF);
    A.tx4 = ((const float4*)txA)[0]; A.ty4 = ((const float4*)tyA)[0];
    B.tx4 = ((const float4*)txA)[0]; B.ty4 = ((const float4*)tyA)[0];

    // Ring links (all cross-wave): ring[0]: role0(w0)->role1(w1);
    // ring[1]: role1(w1)->role2(w0); ring[2]: role2(w0)->role3(w1).
    float4* ringWA = ring[roleA];                       // roleA < 3 always
    const float4* ringRA = ring[(w > 0) ? (roleA - 1) : 0];  // unused if w==0
    float4* ringWB = ring[(w == 0) ? 2 : 0];            // unused if w==1 (role 3)
    const float4* ringRB = ring[roleB - 1];             // roleB > 0 always

    for (int u = 0; u < TOT; ++u) {
        dp_step(A, u, roleA, l, bpa, txA, tyA, ringWA, ringRA);
        dp_step(B, u, roleB, l, bpa, txA, tyA, ringWB, ringRB);
        if ((u & 7) == 7) __syncthreads();
    }

    __threadfence_block();   // drain dec stores (vmcnt) before re-reading
    __syncthreads();

    // ---------------- Backtrack ----------------
    const unsigned* __restrict__ decB = dec + (size_t)b * DEC_WORDS_PER_BATCH;
    // Phase A: tile-rows 128..255 (rows 512..1023) — contiguous 128 KB copy.
    {
        uint4* s4 = (uint4*)sdec;
        const uint4* g4 = (const uint4*)(decB + 128 * 256);
        for (int k = t; k < 8192; k += 128) s4[k] = g4[k];
    }
    __syncthreads();
    if (t == 0) {
        int i = NN - 1, j = MM - 1, n = 0;
        bt_walk4(sdec, 128, 512, i, j, n, path);
        sI = i; sJ = j; sN = n;
    }
    __syncthreads();
    // Phase B: tile-rows 0..127.
    {
        uint4* s4 = (uint4*)sdec;
        const uint4* g4 = (const uint4*)decB;
        for (int k = t; k < 8192; k += 128) s4[k] = g4[k];
    }
    __syncthreads();
    if (t == 0) {
        int i = sI, j = sJ, n = sN;
        bt_walk4(sdec, 0, 0, i, j, n, path);
        sN = n;
    }
    __syncthreads();

    // ---------------- Parallel loss over the path ----------------
    // Replays the 256-thread version exactly: wave w computes old-wave sums
    // s_{2w} and s_{2w+1} in two passes (same per-lane term order, same
    // shuffle tree), then t0 combines (s0+s1)+(s2+s3) as before.
    const float sc0 = subcoef[0], sc1 = subcoef[1];
    const int n = sN;
    #pragma unroll
    for (int po = 0; po < 2; ++po) {
        const int ow = 2 * w + po;          // old wave index
        float acc = 0.0f;
        for (int p = 64 * ow + l; p < n; p += 256) {
            const unsigned e = path[p];
            const int i = (int)(e >> 16), j = (int)(e & 0xffffu);
            acc += fabsf(pxA[i] - txA[j]) * sc0 + fabsf(pyA[i] - tyA[j]) * sc1;
        }
        #pragma unroll
        for (int o = 32; o > 0; o >>= 1) acc += __shfl_down(acc, o);
        if (l == 0) wsum[ow] = acc;
    }
    __syncthreads();
    if (t == 0) atomicAdd(out, (wsum[0] + wsum[1]) + (wsum[2] + wsum[3]));
}

// ------------- Fallback (R1 kernel, only if ws too small) --------------------
__global__ __launch_bounds__(256) void dtw_fallback(
    const float* __restrict__ preds, const float* __restrict__ targs,
    const float* __restrict__ subcoef, unsigned* __restrict__ dec,
    float* __restrict__ out)
{
    const int b = blockIdx.x;
    const int t = threadIdx.x;
    const float INF = __builtin_inff();
    __shared__ float px[NN], py[NN];
    __shared__ float txy[2 * MM];
    __shared__ float bbuf[2][256];

    for (int it = 0; it < NN / 256; ++it) {
        const int idx = it * 256 + t;
        const float4 p4 = ((const float4*)preds)[(size_t)b * NN + idx];
        px[idx] = p4.x; py[idx] = p4.y;
        const float4 t4 = ((const float4*)targs)[(size_t)b * MM + idx];
        txy[2 * idx] = t4.x; txy[2 * idx + 1] = t4.y;
    }
    bbuf[0][t] = INF; bbuf[1][t] = INF;
    __syncthreads();

    float pxr[4], pyr[4], Dp[4];
    #pragma unroll
    for (int r = 0; r < 4; ++r) {
        pxr[r] = px[4 * t + r]; pyr[r] = py[4 * t + r]; Dp[r] = INF;
    }
    float dgB = (t == 0) ? 0.0f : INF;
    unsigned packed = 0;
    unsigned* decB = dec + (size_t)b * 65536;
    for (int s = 0; s < MM + 255; ++s) {
        const int j = s - t;
        const float upB = (t == 0) ? INF : bbuf[(s + 1) & 1][t - 1];
        if (j >= 0 && j < MM) {
            const float txj = txy[2 * j], tyj = txy[2 * j + 1];
            float up = upB, dg = dgB;
            unsigned mbits = 0;
            #pragma unroll
            for (int r = 0; r < 4; ++r) {
                const float dx = pxr[r] - txj, dy = pyr[r] - tyj;
                const float c = sqrtf(dx * dx + dy * dy);
                const float lf = Dp[r];
                const unsigned m = (dg <= up && dg <= lf) ? 0u
                                 : ((up <= lf) ? 1u : 2u);
                mbits |= m << (r * 8 + (j & 3) * 2);
                const float Dc = c + fminf(up, fminf(dg, lf));
                dg = lf; up = Dc; Dp[r] = Dc;
            }
            packed |= mbits;
            if ((j & 3) == 3) { decB[(unsigned)t * 256 + (j >> 2)] = packed; packed = 0; }
            bbuf[s & 1][t] = Dp[3];
        }
        dgB = upB;
        __syncthreads();
    }
    __threadfence_block();
    __syncthreads();
    if (t == 0) {
        const float sc0 = subcoef[0], sc1 = subcoef[1];
        int i = NN - 1, jj = MM - 1;
        float loss = 0.0f;
        int ti = i >> 2, tj = jj >> 2;
        unsigned wv = decB[ti * 256 + tj];
        while (true) {
            const int tjl = (tj > 0) ? tj - 1 : 0;
            const int til = (ti > 0) ? ti - 1 : 0;
            const unsigned wl = decB[ti * 256 + tjl];
            const unsigned wu = decB[til * 256 + tj];
            const unsigned wd = decB[til * 256 + tjl];
            bool done = false;
            while (true) {
                loss += fabsf(px[i] - txy[2 * jj]) * sc0
                      + fabsf(py[i] - txy[2 * jj + 1]) * sc1;
                if ((i | jj) == 0) { done = true; break; }
                const unsigned m = (wv >> (((i & 3) * 4 + (jj & 3)) * 2)) & 3u;
                i -= (m != 2u); jj -= (m != 1u);
                if ((i >> 2) != ti || (jj >> 2) != tj) break;
            }
            if (done) break;
            const int nti = i >> 2, ntj = jj >> 2;
            wv = (nti == ti) ? wl : ((ntj == tj) ? wu : wd);
            ti = nti; tj = ntj;
        }
        atomicAdd(out, loss);
    }
}

extern "C" void kernel_launch(void* const* d_in, const int* in_sizes, int n_in,
                              void* d_out, int out_size, void* d_ws, size_t ws_size,
                              hipStream_t stream) {
    const float* preds   = (const float*)d_in[0];
    const float* targs   = (const float*)d_in[1];
    const float* subcoef = (const float*)d_in[2];
    float* out = (float*)d_out;
    unsigned* dec = (unsigned*)d_ws;   // 8 MB

    init_kernel<<<1, 1, 0, stream>>>(out);
    if (ws_size >= REQ_WS) {
        dtw_fused<<<BATCH, 128, 0, stream>>>(preds, targs, subcoef, dec, out);
    } else {
        dtw_fallback<<<BATCH, 256, 0, stream>>>(preds, targs, subcoef, dec, out);
    }
}

// Round 2
// 608.903 us; speedup vs baseline: 1.3190x; 1.3190x over previous
//
#include <hip/hip_runtime.h>
#include <math.h>

#define BATCH 32
#define NN 1024
#define MM 1024
#define RR 4                    // rows per lane
#define CC 4                    // cols per superstep
#define LANES 64
#define NWAVE 4
#define TPB (MM / 4)            // tile-columns = lane-local supersteps (256)
#define NSUP (TPB + LANES - 1)  // 319 supersteps per wave
#define LAG 72                  // wave-to-wave lag (63 lane skew + 9 margin)
#define TOT (NSUP + (NWAVE - 1) * LAG)   // 535 iterations
#define DEPTH 32                // LDS boundary ring depth (float4 entries)
#define DEC_WORDS_PER_BATCH ((NN / 4) * (MM / 4))     // 65536
#define DEC_BYTES ((size_t)BATCH * DEC_WORDS_PER_BATCH * 4)   // 8 MB
#define REQ_WS DEC_BYTES
#define LPATH (NN + MM - 1)     // 2047

__global__ void init_kernel(float* out) { out[0] = 0.0f; }

// ---- Backtrack word-walk (4x4 tile words, 3-candidate prefetch) -------------
// sdec is in plain [row_local][jc] layout (un-permuted during the LDS copy).
__device__ inline void bt_walk4(const unsigned* __restrict__ sdec, int roff,
                                int iLow, int& i, int& j, int& n,
                                unsigned* __restrict__ path)
{
    int ri = i >> 2, jc = j >> 2;
    unsigned w = sdec[(ri - roff) * 256 + jc];
    while (true) {
        const int base = (ri - roff) * 256 + jc;
        const unsigned wl = sdec[(jc > 0)    ? base - 1   : base];
        const unsigned wu = sdec[(ri > roff) ? base - 256 : base];
        const unsigned wd = sdec[(ri > roff && jc > 0) ? base - 257 : base];
        bool done = false, susp = false;
        while (true) {
            path[n++] = ((unsigned)i << 16) | (unsigned)j;
            if ((i | j) == 0) { done = true; break; }
            const unsigned m = (w >> (((i & 3) * 4 + (j & 3)) * 2)) & 3u;
            i -= (m != 2u); j -= (m != 1u);
            if (i < iLow) { susp = true; break; }
            if ((i >> 2) != ri || (j >> 2) != jc) break;
        }
        if (done || susp) break;
        const int nri = i >> 2, njc = j >> 2;
        w = (nri == ri) ? wl : ((njc == jc) ? wu : wd);
        ri = nri; jc = njc;
    }
}

// ---- Fused DP + backtrack: 32 blocks (one per batch) x 256 threads ----------
// Wave w owns rows [256w, 256w+256); lane l owns rows i0=256w+4l..i0+3.
// Lane l's local superstep ul covers cols j0=4(ul-l)..j0+3. Wave w runs at
// global iteration u = ul + LAG*w. Intra-wave boundary: 4 __shfl_up per
// superstep. Cross-wave boundary: 32-deep LDS float4 ring.
//
// DECISION STORE LAYOUT (the R2 change): the old store decT[jc] was a
// 64-lane scatter at 1024B stride (64 distinct cache lines per wave per
// superstep) that had to drain at every vmcnt(0) barrier. New layout:
//   word(b, w, ul, l) = dec[b*65536 + w*16384 + (ul&255)*64 + l]
// ul is wave-uniform => each superstep's store is ONE contiguous 256B line.
// Bijective with the old [ri][jc] layout via jc = ((ul&255) - l) & 255,
// ri = 64w + l; the backtrack LDS copy un-permutes to [ri][jc].
__global__ __launch_bounds__(256, 1) void dtw_fused(
    const float* __restrict__ preds, const float* __restrict__ targs,
    const float* __restrict__ subcoef, unsigned* __restrict__ dec,
    float* __restrict__ out)
{
    const int b = blockIdx.x, t = threadIdx.x;
    const int l = t & 63, w = t >> 6;
    const float INF = __builtin_inff();

    __shared__ float pxA[NN], pyA[NN], txA[MM], tyA[MM];   // 16 KB
    __shared__ float4 ring[NWAVE - 1][DEPTH];              // 1.5 KB
    __shared__ unsigned sdec[128 * 256];                   // 128 KB
    __shared__ unsigned path[LPATH + 1];                   // 8 KB
    __shared__ int sI, sJ, sN;
    __shared__ float wsum[NWAVE];

    for (int it = 0; it < NN / 256; ++it) {
        const int idx = it * 256 + t;
        const float4 p4 = ((const float4*)preds)[(size_t)b * NN + idx];
        pxA[idx] = p4.x; pyA[idx] = p4.y;
        const float4 t4 = ((const float4*)targs)[(size_t)b * MM + idx];
        txA[idx] = t4.x; tyA[idx] = t4.y;
    }
    __syncthreads();

    // ---------------- DP ----------------
    const int i0 = (w << 8) + (l << 2);
    const float4 px4 = ((const float4*)pxA)[i0 >> 2];
    const float4 py4 = ((const float4*)pyA)[i0 >> 2];
    const float px[RR] = {px4.x, px4.y, px4.z, px4.w};
    const float py[RR] = {py4.x, py4.y, py4.z, py4.w};
    // Coalesced packed store base: + b*65536 + w*16384 + l
    unsigned* __restrict__ decW =
        dec + (size_t)b * DEC_WORDS_PER_BATCH + ((size_t)w << 14) + (size_t)l;

    float Dp[RR], Dbot[CC], bv[CC];
    #pragma unroll
    for (int r = 0; r < RR; ++r) Dp[r] = INF;
    #pragma unroll
    for (int c = 0; c < CC; ++c) { Dbot[c] = INF; bv[c] = INF; }
    // dg for (i0, j0) = previous superstep's bv[3]. Seed: dg=0 at global (0,0)
    // reproduces the reference's inf->0 substitution exactly (argmin=0 too).
    float bndRet = (w == 0 && l == 0) ? 0.0f : INF;
    float4 gcur = make_float4(INF, INF, INF, INF);
    float4 tx4 = ((const float4*)txA)[0], ty4 = ((const float4*)tyA)[0];
    const float4* __restrict__ ringR = ring[(w > 0) ? (w - 1) : 0];

    for (int u = 0; u < TOT; ++u) {
        const int ul = u - LAG * w;      // this wave's local superstep
        if (l == 0) {                    // boundary row from previous band
            const bool gb = (w > 0) && (ul >= 0) && (ul < TPB);
            bv[0] = gb ? gcur.x : INF; bv[1] = gb ? gcur.y : INF;
            bv[2] = gb ? gcur.z : INF; bv[3] = gb ? gcur.w : INF;
        }
        const bool act = (ul >= l) && (ul < l + TPB);
        if (act) {
            const float cx[CC] = {tx4.x, tx4.y, tx4.z, tx4.w};
            const float cy[CC] = {ty4.x, ty4.y, ty4.z, ty4.w};
            float cost[RR][CC];
            #pragma unroll
            for (int c = 0; c < CC; ++c)
                #pragma unroll
                for (int r = 0; r < RR; ++r) {
                    const float dx = px[r] - cx[c], dy = py[r] - cy[c];
                    cost[r][c] = __builtin_amdgcn_sqrtf(dx * dx + dy * dy);
                }
            unsigned word = 0;
            #pragma unroll
            for (int c = 0; c < CC; ++c) {
                float up = bv[c];                       // D[i0-1][j0+c]
                float dg = (c == 0) ? bndRet : bv[c - 1];
                #pragma unroll
                for (int r = 0; r < RR; ++r) {
                    const float lf = Dp[r];             // D[i0+r][j0+c-1]
                    // JAX argmin over [dg, up, lf], first-minimum tie order.
                    const unsigned m = (dg <= up && dg <= lf) ? 0u
                                     : ((up <= lf) ? 1u : 2u);
                    const float D = cost[r][c] + fminf(dg, fminf(up, lf));
                    word |= m << ((r * 4 + c) * 2);
                    dg = lf; up = D; Dp[r] = D;
                }
                Dbot[c] = up;
            }
            decW[(ul & 255) << 6] = word;               // one 256B line / wave
            if (l == LANES - 1 && w < NWAVE - 1)        // publish bottom row
                ring[w][ul & (DEPTH - 1)] =
                    make_float4(Dbot[0], Dbot[1], Dbot[2], Dbot[3]);
        }
        // Uniform epilogue: retain dg, exchange boundary, prefetch next.
        bndRet = bv[CC - 1];
        #pragma unroll
        for (int c = 0; c < CC; ++c) bv[c] = __shfl_up(Dbot[c], 1);
        const int un = ul + 1;
        if (un >= l && un < l + TPB) {
            const int jn = CC * (un - l);
            tx4 = ((const float4*)txA)[jn >> 2];
            ty4 = ((const float4*)tyA)[jn >> 2];
        }
        // Wave-uniform condition; broadcast read, only lane 0's copy is used.
        if (w > 0 && un >= 0 && un < TPB)
            gcur = ringR[(un + 63) & (DEPTH - 1)];
        if ((u & 7) == 7) __syncthreads();
    }

    __threadfence_block();   // drain dec stores (vmcnt) before re-reading
    __syncthreads();

    // ---------------- Backtrack ----------------
    const unsigned* __restrict__ decB = dec + (size_t)b * DEC_WORDS_PER_BATCH;
    // Phase A: waves 2,3 (tile-rows 128..255) — contiguous 128 KB, un-permute
    // packed (w, q, l) -> sdec[row_local][jc], jc = (q - l) & 255.
    {
        const uint4* g4 = (const uint4*)(decB + 32768);
        for (int k = t; k < 8192; k += 256) {
            const uint4 v = g4[k];
            const int kb = k << 2;            // word offset in 32768-word window
            const int wv = kb >> 14;          // 0,1 -> wave 2,3
            const int rem = kb & 16383;
            const int q = rem >> 6;
            const int lb = rem & 63;
            const unsigned wd[4] = {v.x, v.y, v.z, v.w};
            #pragma unroll
            for (int e = 0; e < 4; ++e) {
                const int ll = lb + e;
                const int row = (wv << 6) + ll;       // tile-row - 128
                const int jc = (q - ll) & 255;
                sdec[(row << 8) + jc] = wd[e];
            }
        }
    }
    __syncthreads();
    if (t == 0) {
        int i = NN - 1, j = MM - 1, n = 0;
        bt_walk4(sdec, 128, 512, i, j, n, path);
        sI = i; sJ = j; sN = n;
    }
    __syncthreads();
    // Phase B: waves 0,1 (tile-rows 0..127).
    {
        const uint4* g4 = (const uint4*)decB;
        for (int k = t; k < 8192; k += 256) {
            const uint4 v = g4[k];
            const int kb = k << 2;
            const int wv = kb >> 14;          // 0,1 -> wave 0,1
            const int rem = kb & 16383;
            const int q = rem >> 6;
            const int lb = rem & 63;
            const unsigned wd[4] = {v.x, v.y, v.z, v.w};
            #pragma unroll
            for (int e = 0; e < 4; ++e) {
                const int ll = lb + e;
                const int row = (wv << 6) + ll;       // tile-row
                const int jc = (q - ll) & 255;
                sdec[(row << 8) + jc] = wd[e];
            }
        }
    }
    __syncthreads();
    if (t == 0) {
        int i = sI, j = sJ, n = sN;
        bt_walk4(sdec, 0, 0, i, j, n, path);
        sN = n;
    }
    __syncthreads();

    // ---------------- Parallel loss over the path ----------------
    const float sc0 = subcoef[0], sc1 = subcoef[1];
    const int n = sN;
    float acc = 0.0f;
    for (int p = t; p < n; p += 256) {
        const unsigned e = path[p];
        const int i = (int)(e >> 16), j = (int)(e & 0xffffu);
        acc += fabsf(pxA[i] - txA[j]) * sc0 + fabsf(pyA[i] - tyA[j]) * sc1;
    }
    #pragma unroll
    for (int o = 32; o > 0; o >>= 1) acc += __shfl_down(acc, o);
    if ((t & 63) == 0) wsum[t >> 6] = acc;
    __syncthreads();
    if (t == 0) atomicAdd(out, (wsum[0] + wsum[1]) + (wsum[2] + wsum[3]));
}

// ------------- Fallback (R1 kernel, only if ws too small) --------------------
__global__ __launch_bounds__(256) void dtw_fallback(
    const float* __restrict__ preds, const float* __restrict__ targs,
    const float* __restrict__ subcoef, unsigned* __restrict__ dec,
    float* __restrict__ out)
{
    const int b = blockIdx.x;
    const int t = threadIdx.x;
    const float INF = __builtin_inff();
    __shared__ float px[NN], py[NN];
    __shared__ float txy[2 * MM];
    __shared__ float bbuf[2][256];

    for (int it = 0; it < NN / 256; ++it) {
        const int idx = it * 256 + t;
        const float4 p4 = ((const float4*)preds)[(size_t)b * NN + idx];
        px[idx] = p4.x; py[idx] = p4.y;
        const float4 t4 = ((const float4*)targs)[(size_t)b * MM + idx];
        txy[2 * idx] = t4.x; txy[2 * idx + 1] = t4.y;
    }
    bbuf[0][t] = INF; bbuf[1][t] = INF;
    __syncthreads();

    float pxr[4], pyr[4], Dp[4];
    #pragma unroll
    for (int r = 0; r < 4; ++r) {
        pxr[r] = px[4 * t + r]; pyr[r] = py[4 * t + r]; Dp[r] = INF;
    }
    float dgB = (t == 0) ? 0.0f : INF;
    unsigned packed = 0;
    unsigned* decB = dec + (size_t)b * 65536;
    for (int s = 0; s < MM + 255; ++s) {
        const int j = s - t;
        const float upB = (t == 0) ? INF : bbuf[(s + 1) & 1][t - 1];
        if (j >= 0 && j < MM) {
            const float txj = txy[2 * j], tyj = txy[2 * j + 1];
            float up = upB, dg = dgB;
            unsigned mbits = 0;
            #pragma unroll
            for (int r = 0; r < 4; ++r) {
                const float dx = pxr[r] - txj, dy = pyr[r] - tyj;
                const float c = sqrtf(dx * dx + dy * dy);
                const float lf = Dp[r];
                const unsigned m = (dg <= up && dg <= lf) ? 0u
                                 : ((up <= lf) ? 1u : 2u);
                mbits |= m << (r * 8 + (j & 3) * 2);
                const float Dc = c + fminf(up, fminf(dg, lf));
                dg = lf; up = Dc; Dp[r] = Dc;
            }
            packed |= mbits;
            if ((j & 3) == 3) { decB[(unsigned)t * 256 + (j >> 2)] = packed; packed = 0; }
            bbuf[s & 1][t] = Dp[3];
        }
        dgB = upB;
        __syncthreads();
    }
    __threadfence_block();
    __syncthreads();
    if (t == 0) {
        const float sc0 = subcoef[0], sc1 = subcoef[1];
        int i = NN - 1, jj = MM - 1;
        float loss = 0.0f;
        int ti = i >> 2, tj = jj >> 2;
        unsigned wv = decB[ti * 256 + tj];
        while (true) {
            const int tjl = (tj > 0) ? tj - 1 : 0;
            const int til = (ti > 0) ? ti - 1 : 0;
            const unsigned wl = decB[ti * 256 + tjl];
            const unsigned wu = decB[til * 256 + tj];
            const unsigned wd = decB[til * 256 + tjl];
            bool done = false;
            while (true) {
                loss += fabsf(px[i] - txy[2 * jj]) * sc0
                      + fabsf(py[i] - txy[2 * jj + 1]) * sc1;
                if ((i | jj) == 0) { done = true; break; }
                const unsigned m = (wv >> (((i & 3) * 4 + (jj & 3)) * 2)) & 3u;
                i -= (m != 2u); jj -= (m != 1u);
                if ((i >> 2) != ti || (jj >> 2) != tj) break;
            }
            if (done) break;
            const int nti = i >> 2, ntj = jj >> 2;
            wv = (nti == ti) ? wl : ((ntj == tj) ? wu : wd);
            ti = nti; tj = ntj;
        }
        atomicAdd(out, loss);
    }
}

extern "C" void kernel_launch(void* const* d_in, const int* in_sizes, int n_in,
                              void* d_out, int out_size, void* d_ws, size_t ws_size,
                              hipStream_t stream) {
    const float* preds   = (const float*)d_in[0];
    const float* targs   = (const float*)d_in[1];
    const float* subcoef = (const float*)d_in[2];
    float* out = (float*)d_out;
    unsigned* dec = (unsigned*)d_ws;   // 8 MB

    init_kernel<<<1, 1, 0, stream>>>(out);
    if (ws_size >= REQ_WS) {
        dtw_fused<<<BATCH, 256, 0, stream>>>(preds, targs, subcoef, dec, out);
    } else {
        dtw_fallback<<<BATCH, 256, 0, stream>>>(preds, targs, subcoef, dec, out);
    }
}